// Round 13
// baseline (731.933 us; speedup 1.0000x reference)
//
#include <hip/hip_runtime.h>
#include <math.h>

#define NN   1024
#define DD   256
#define NCLS 10

#define TI 64      // i rows per block
#define TJ 128     // j cols per block
#define DC 32      // d chunk per block (8 quads/row)
#define DSPLIT 8
#define NBLK ((NN / TI) * (NN / TJ) * DSPLIT)   // 1024
#define NSLOT ((NN / TJ) * DSPLIT)              // 64 slots per i-row

typedef float f32x2 __attribute__((ext_vector_type(2)));
typedef float f32x4 __attribute__((ext_vector_type(4)));

// Force VOP3P packed f32 (v_pk_*): halves arithmetic issue slots.
#define PK_FMA(d, a, b, c) \
    asm("v_pk_fma_f32 %0, %1, %2, %3" : "=v"(d) : "v"(a), "v"(b), "v"(c))
#define PK_ADD(d, a, b) \
    asm("v_pk_add_f32 %0, %1, %2" : "=v"(d) : "v"(a), "v"(b))

// Placement: i-side row r, d-quad q -> physical quad (q + (r>>2)) & 7
//            j-side row r, d-quad q -> physical quad (q + (r>>3)) & 7
// Read step k: thread(ty) i-quad (k+ty)&7, thread(tx) j-quad (k+tx)&7.
// Output: UNWEIGHTED per-i-row sums (lp over eq-j, ln over ne-j); weighting
// deferred to finalize (weights depend only on ti) -> no count_kernel launch.
__global__ __launch_bounds__(256) void pair_kernel(
    const float* __restrict__ fm_s, const float* __restrict__ fm_t,
    const float* __restrict__ lv, const long long* __restrict__ tgt,
    float* __restrict__ val)
{
    __shared__ float Al[TI * DC];   // 8 KB : fs^2*iv + 0.5*lv
    __shared__ float Bl[TI * DC];   // 8 KB : -2*fs*iv
    __shared__ float Vl[TI * DC];   // 8 KB : iv
    __shared__ float Fl[TJ * DC];   // 16 KB : fm_t     => 40960 B exactly

    const int bid  = blockIdx.x;
    const int tile = bid >> 3;
    const int kd   = bid & 7;
    const int jt   = tile & 7;
    const int i0   = (tile >> 3) * TI;
    const int j0   = jt * TJ;
    const int doff = kd * DC;

    const int tid  = threadIdx.x;
    const int tx   = tid & 15;       // j-group: 8 cols
    const int ty   = tid >> 4;       // i-group: 4 rows
    const int lane = tid & 63;

    const int* tgt32 = (const int*)tgt;   // int64 low words, values 0..9

    // ---- staging (float4 loads, b128 LDS writes, swizzled placement) ----
    const int srow = tid >> 3;       // 0..31
    const int sq   = tid & 7;        // source d-quad
#pragma unroll
    for (int p = 0; p < 4; ++p) {    // teacher tile: 128 rows
        const int r = p * 32 + srow;
        f32x4 v = *(const f32x4*)&fm_t[(j0 + r) * DD + doff + sq * 4];
        const int phys = (sq + (r >> 3)) & 7;
        *(f32x4*)&Fl[r * DC + phys * 4] = v;
    }
#pragma unroll
    for (int p = 0; p < 2; ++p) {    // student side: 64 rows
        const int r = p * 32 + srow;
        const int g = (i0 + r) * DD + doff + sq * 4;
        f32x4 fs = *(const f32x4*)&fm_s[g];
        f32x4 l  = *(const f32x4*)&lv[g];
        f32x4 A, B, V;
#pragma unroll
        for (int e = 0; e < 4; ++e) {
            const float iv = 0.5f * __expf(-l[e]);   // 1/(2e^l+1e-12) to ~2e-6 rel
            const float fsiv = fs[e] * iv;
            A[e] = fmaf(fsiv, fs[e], 0.5f * l[e]);
            B[e] = -2.0f * fsiv;
            V[e] = iv;
        }
        const int phys = (sq + (r >> 2)) & 7;
        *(f32x4*)&Al[r * DC + phys * 4] = A;
        *(f32x4*)&Bl[r * DC + phys * 4] = B;
        *(f32x4*)&Vl[r * DC + phys * 4] = V;
    }

    __syncthreads();

    // scalar accumulators (64 VGPR)
    float s1[4][8], s2[4][8];
#pragma unroll
    for (int a = 0; a < 4; ++a)
#pragma unroll
        for (int b = 0; b < 8; ++b) { s1[a][b] = 0.f; s2[a][b] = 0.f; }

    // ---- main loop: 8 steps, d-quad k each; imm-offset b128 reads ----
#pragma unroll
    for (int k = 0; k < 8; ++k) {
        const f32x4* pf = (const f32x4*)&Fl[tx * 256 + ((k + tx) & 7) * 4];
        f32x4 f[8];
#pragma unroll
        for (int rj = 0; rj < 8; ++rj) f[rj] = pf[rj * 8];

        const int iq = ((k + ty) & 7) * 4;
        const f32x4* pa = (const f32x4*)&Al[ty * 128 + iq];
        const f32x4* pb = (const f32x4*)&Bl[ty * 128 + iq];
        const f32x4* pv = (const f32x4*)&Vl[ty * 128 + iq];
#pragma unroll
        for (int ri = 0; ri < 4; ++ri) {
            const f32x4 fa = pa[ri * 8];
            const f32x4 fb = pb[ri * 8];
            const f32x4 fv = pv[ri * 8];
#pragma unroll
            for (int rj = 0; rj < 8; ++rj) {
                const f32x2 f01 = f[rj].lo, f23 = f[rj].hi;
                f32x2 u01, u23, t01, t23, st;
                // Horner: t = (V*f + B)*f + A
                PK_FMA(u01, fv.lo, f01, fb.lo);
                PK_FMA(u23, fv.hi, f23, fb.hi);
                PK_FMA(t01, u01, f01, fa.lo);
                PK_FMA(t23, u23, f23, fa.hi);
                PK_ADD(st, t01, t23);
                s1[ri][rj] += st.x + st.y;
                s2[ri][rj] += (fabsf(t01.x) + fabsf(t01.y))
                            + (fabsf(t23.x) + fabsf(t23.y));
            }
        }
    }

    // ---- epilogue: unweighted eq/ne split, reduce across the 16 tx lanes ----
#pragma unroll
    for (int ri = 0; ri < 4; ++ri) {
        const int t = tgt32[(i0 + ty * 4 + ri) * 2];
        float lpe = 0.f, lnn = 0.f;
#pragma unroll
        for (int rj = 0; rj < 8; ++rj) {
            const int tj = tgt32[(j0 + tx * 8 + rj) * 2];
            const float lp = 0.5f * (s2[ri][rj] + s1[ri][rj]);
            const float ln = 0.5f * (s2[ri][rj] - s1[ri][rj]);
            if (t == tj) lpe += lp; else lnn += ln;
        }
        // reduce across tx (16 consecutive lanes share ty)
#pragma unroll
        for (int off = 8; off > 0; off >>= 1) {
            lpe += __shfl_down(lpe, off);
            lnn += __shfl_down(lnn, off);
        }
        if ((lane & 15) == 0) {
            f32x2 o; o.x = lpe; o.y = lnn;
            *(f32x2*)&val[((i0 + ty * 4 + ri) * NSLOT + jt * 8 + kd) * 2] = o;
        }
    }
}

// histogram + weighting + total reduction, one block
__global__ __launch_bounds__(256) void finalize_kernel(const long long* __restrict__ tgt,
                                                       const float* __restrict__ val,
                                                       float* __restrict__ out) {
    __shared__ int   ch[NCLS];
    __shared__ float red[256];
    const int tid = threadIdx.x;
    const int* tgt32 = (const int*)tgt;

    if (tid < NCLS) ch[tid] = 0;
    __syncthreads();
#pragma unroll
    for (int k = 0; k < NN / 256; ++k)
        atomicAdd(&ch[tgt32[(k * 256 + tid) * 2]], 1);
    __syncthreads();

    float s = 0.f;
#pragma unroll
    for (int rr = 0; rr < NN / 256; ++rr) {
        const int row = rr * 256 + tid;
        float lpe = 0.f, lnn = 0.f;
        const f32x2* p = (const f32x2*)&val[row * NSLOT * 2];
#pragma unroll 8
        for (int k = 0; k < NSLOT; ++k) { lpe += p[k].x; lnn += p[k].y; }
        const int   c  = ch[tgt32[row * 2]];
        s += lpe / (float)c + lnn / (float)(NN - c);
    }
    red[tid] = s;
    __syncthreads();
    for (int st = 128; st > 0; st >>= 1) {
        if (tid < st) red[tid] += red[tid + st];
        __syncthreads();
    }
    if (tid == 0) out[0] = red[0] * (1.0f / (float)NN);
}

extern "C" void kernel_launch(void* const* d_in, const int* in_sizes, int n_in,
                              void* d_out, int out_size, void* d_ws, size_t ws_size,
                              hipStream_t stream) {
    const float* fm_s    = (const float*)d_in[0];
    const float* fm_t    = (const float*)d_in[1];
    const float* lv      = (const float*)d_in[2];
    const long long* tgt = (const long long*)d_in[3];
    // fusion_true (d_in[4]) == 0 path implemented

    float* val = (float*)d_ws;   // [NN][NSLOT][2] floats = 512 KB

    hipLaunchKernelGGL(pair_kernel, dim3(NBLK), dim3(256), 0, stream,
                       fm_s, fm_t, lv, tgt, val);
    hipLaunchKernelGGL(finalize_kernel, dim3(1), dim3(256), 0, stream,
                       tgt, val, (float*)d_out);
}

// Round 14
// 36.533 us; speedup vs baseline: 20.0347x; 20.0347x over previous
//
#include <hip/hip_runtime.h>
#include <math.h>

#define NN   1024
#define DD   256
#define NCLS 10

#define TI 64      // i rows per block
#define TJ 128     // j cols per block
#define DC 32      // d chunk per block (8 quads/row)
#define DSPLIT 8
#define NBLK ((NN / TI) * (NN / TJ) * DSPLIT)   // 1024

typedef float f32x2 __attribute__((ext_vector_type(2)));
typedef float f32x4 __attribute__((ext_vector_type(4)));

__global__ __launch_bounds__(256) void count_kernel(const long long* __restrict__ tgt,
                                                    int* __restrict__ counts) {
    __shared__ int c[NCLS];
    int tid = threadIdx.x;
    if (tid < NCLS) c[tid] = 0;
    __syncthreads();
    for (int k = tid; k < NN; k += 256) atomicAdd(&c[(int)tgt[k]], 1);
    __syncthreads();
    if (tid < NCLS) counts[tid] = c[tid];
}

// Placement: i-side row r, d-quad q -> physical quad (q + (r>>2)) & 7
//            j-side row r, d-quad q -> physical quad (q + (r>>3)) & 7
// Read step k: thread(ty) i-quad (k+ty)&7, thread(tx) j-quad (k+tx)&7 -> both hold d-quad k.
__global__ __launch_bounds__(256) void pair_kernel(
    const float* __restrict__ fm_s, const float* __restrict__ fm_t,
    const float* __restrict__ lv, const long long* __restrict__ tgt,
    const int* __restrict__ counts, float* __restrict__ partials)
{
    __shared__ float Al[TI * DC];   // 8 KB  : fs^2*iv + 0.5*lv
    __shared__ float Bl[TI * DC];   // 8 KB  : -2*fs*iv
    __shared__ float Vl[TI * DC];   // 8 KB  : iv
    __shared__ float Fl[TJ * DC];   // 16 KB : fm_t     => 40960 B exactly

    const int bid  = blockIdx.x;
    const int tile = bid >> 3;
    const int kd   = bid & 7;
    const int i0   = (tile >> 3) * TI;
    const int j0   = (tile & 7) * TJ;
    const int doff = kd * DC;

    const int tid  = threadIdx.x;
    const int tx   = tid & 15;       // j-group: 8 cols
    const int ty   = tid >> 4;       // i-group: 4 rows
    const int lane = tid & 63;
    const int w    = tid >> 6;

    // ---- staging (float4 loads, b128 LDS writes, swizzled placement) ----
    const int srow = tid >> 3;       // 0..31
    const int sq   = tid & 7;        // source d-quad
#pragma unroll
    for (int p = 0; p < 4; ++p) {    // teacher tile: 128 rows
        const int r = p * 32 + srow;
        f32x4 v = *(const f32x4*)&fm_t[(j0 + r) * DD + doff + sq * 4];
        const int phys = (sq + (r >> 3)) & 7;
        *(f32x4*)&Fl[r * DC + phys * 4] = v;
    }
#pragma unroll
    for (int p = 0; p < 2; ++p) {    // student side: 64 rows
        const int r = p * 32 + srow;
        const int g = (i0 + r) * DD + doff + sq * 4;
        f32x4 fs = *(const f32x4*)&fm_s[g];
        f32x4 l  = *(const f32x4*)&lv[g];
        f32x4 A, B, V;
#pragma unroll
        for (int e = 0; e < 4; ++e) {
            const float iv = 0.5f * __expf(-l[e]);   // 1/(2e^l+1e-12) to ~2e-6 rel
            const float fsiv = fs[e] * iv;
            A[e] = fmaf(fsiv, fs[e], 0.5f * l[e]);
            B[e] = -2.0f * fsiv;
            V[e] = iv;
        }
        const int phys = (sq + (r >> 2)) & 7;
        *(f32x4*)&Al[r * DC + phys * 4] = A;
        *(f32x4*)&Bl[r * DC + phys * 4] = B;
        *(f32x4*)&Vl[r * DC + phys * 4] = V;
    }

    // hoist epilogue metadata loads (overlap with LDS fill + compute)
    const int* tgt32 = (const int*)tgt;   // int64 low words, values 0..9
    int ti_r[4], tj_r[8];
    float wp_r[4], wn_r[4];
#pragma unroll
    for (int ri = 0; ri < 4; ++ri) {
        ti_r[ri] = tgt32[(i0 + ty * 4 + ri) * 2];
        const int cnt = counts[ti_r[ri]];
        wp_r[ri] = 1.0f / (float)cnt;
        wn_r[ri] = 1.0f / (float)(NN - cnt);
    }
#pragma unroll
    for (int rj = 0; rj < 8; ++rj) tj_r[rj] = tgt32[(j0 + tx * 8 + rj) * 2];

    __syncthreads();

    // s1 packed (f32x2) per pair; s2 scalar (abs-adds fold into VOP3 modifiers)
    f32x2 s1v[4][8];
    float s2[4][8];
#pragma unroll
    for (int a = 0; a < 4; ++a)
#pragma unroll
        for (int b = 0; b < 8; ++b) { s1v[a][b] = (f32x2)(0.f); s2[a][b] = 0.f; }

    // ---- main loop: 8 steps, d-quad k each; imm-offset b128 reads ----
#pragma unroll
    for (int k = 0; k < 8; ++k) {
        const int iq = ((k + ty) & 7) * 4;
        const f32x4* pa = (const f32x4*)&Al[ty * 128 + iq];  // +r*32 floats = idx r*8
        const f32x4* pb = (const f32x4*)&Bl[ty * 128 + iq];
        const f32x4* pv = (const f32x4*)&Vl[ty * 128 + iq];
        f32x4 fa[4], fb[4], fv[4];
#pragma unroll
        for (int r = 0; r < 4; ++r) {
            fa[r] = pa[r * 8];
            fb[r] = pb[r * 8];
            fv[r] = pv[r * 8];
        }
        const f32x4* pf = (const f32x4*)&Fl[tx * 256 + ((k + tx) & 7) * 4];
#pragma unroll
        for (int rj = 0; rj < 8; ++rj) {
            const f32x4 f = pf[rj * 8];
            const f32x2 f01 = f.lo, f23 = f.hi;
            const f32x2 g01 = f01 * f01, g23 = f23 * f23;
#pragma unroll
            for (int ri = 0; ri < 4; ++ri) {
                const f32x2 t01 = __builtin_elementwise_fma(g01, fv[ri].lo,
                                    __builtin_elementwise_fma(f01, fb[ri].lo, fa[ri].lo));
                const f32x2 t23 = __builtin_elementwise_fma(g23, fv[ri].hi,
                                    __builtin_elementwise_fma(f23, fb[ri].hi, fa[ri].hi));
                s1v[ri][rj] += (t01 + t23);                 // 2 packed ops
                s2[ri][rj] += (fabsf(t01.x) + fabsf(t01.y)) // 4 abs-adds (mods free)
                            + (fabsf(t23.x) + fabsf(t23.y));
            }
        }
    }

    // ---- epilogue: collapse packed s1, masked row-normalized weighting ----
    float csum = 0.f;
#pragma unroll
    for (int ri = 0; ri < 4; ++ri) {
#pragma unroll
        for (int rj = 0; rj < 8; ++rj) {
            const float s1 = s1v[ri][rj].x + s1v[ri][rj].y;
            const float lp = 0.5f * (s2[ri][rj] + s1);
            const float ln = 0.5f * (s2[ri][rj] - s1);
            csum += (ti_r[ri] == tj_r[rj]) ? lp * wp_r[ri] : ln * wn_r[ri];
        }
    }

#pragma unroll
    for (int off = 32; off > 0; off >>= 1) csum += __shfl_down(csum, off);
    __syncthreads();
    if (lane == 0) Al[w] = csum;
    __syncthreads();
    if (tid == 0) partials[bid] = (Al[0] + Al[1]) + (Al[2] + Al[3]);
}

__global__ __launch_bounds__(256) void finalize_kernel(const float* __restrict__ partials,
                                                       float* __restrict__ out) {
    __shared__ float red[256];
    const int tid = threadIdx.x;
    red[tid] = (partials[tid] + partials[tid + 256]) +
               (partials[tid + 512] + partials[tid + 768]);
    __syncthreads();
    for (int s = 128; s > 0; s >>= 1) {
        if (tid < s) red[tid] += red[tid + s];
        __syncthreads();
    }
    if (tid == 0) out[0] = red[0] * (1.0f / (float)NN);
}

extern "C" void kernel_launch(void* const* d_in, const int* in_sizes, int n_in,
                              void* d_out, int out_size, void* d_ws, size_t ws_size,
                              hipStream_t stream) {
    const float* fm_s    = (const float*)d_in[0];
    const float* fm_t    = (const float*)d_in[1];
    const float* lv      = (const float*)d_in[2];
    const long long* tgt = (const long long*)d_in[3];
    // fusion_true (d_in[4]) == 0 path implemented

    int*   counts   = (int*)d_ws;
    float* partials = (float*)((char*)d_ws + 64);

    hipLaunchKernelGGL(count_kernel, dim3(1), dim3(256), 0, stream, tgt, counts);
    hipLaunchKernelGGL(pair_kernel, dim3(NBLK), dim3(256), 0, stream,
                       fm_s, fm_t, lv, tgt, counts, partials);
    hipLaunchKernelGGL(finalize_kernel, dim3(1), dim3(256), 0, stream,
                       partials, (float*)d_out);
}